// Round 10
// baseline (199.095 us; speedup 1.0000x reference)
//
#include <hip/hip_runtime.h>
#include <hip/hip_bf16.h>

#define DM 256
#define DSZ 16
#define SEQ 4096

typedef __attribute__((ext_vector_type(8))) short bf16x8;
typedef __attribute__((ext_vector_type(4))) float f32x4;

__device__ inline short f2bf(float f) {
    union { float f; unsigned u; } v; v.f = f;
    unsigned r = v.u + 0x7fff + ((v.u >> 16) & 1);   // RNE
    return (short)(r >> 16);
}
__device__ inline float bf2f(short s) {
    union { unsigned u; float f; } v;
    v.u = ((unsigned)(unsigned short)s) << 16;
    return v.f;
}

// ---------------- K0: convert weights to bf16 (Wc zero-padded K=16->32) ----
__global__ __launch_bounds__(256) void k0_convert(
        const float* __restrict__ Wg, const float* __restrict__ Wc,
        const float* __restrict__ Wb,
        short* __restrict__ Wg_bf, short* __restrict__ Wc_bf32,
        short* __restrict__ Wb_bf) {
    int i = blockIdx.x * 256 + threadIdx.x;
    int stride = gridDim.x * 256;
    for (int idx = i; idx < 256 * 256; idx += stride) Wg_bf[idx] = f2bf(Wg[idx]);
    for (int idx = i; idx < 256 * 32; idx += stride) {
        int c = idx >> 5, k = idx & 31;
        Wc_bf32[idx] = (k < 16) ? f2bf(Wc[c * 16 + k]) : (short)0;
    }
    for (int idx = i; idx < 16 * 256; idx += stride) Wb_bf[idx] = f2bf(Wb[idx]);
}

// ---------------- KF: fully fused Bx-GEMM + scan + gate GEMM + mix + LN ----
// 32-row tiles (one batch, 32 consecutive t). 16-row warmup staged in-block.
// Phases: stage | BxGEMM(w1-3) | scan(w0 lanes0-15) + gateGEMM(all) | mix | LN | store.
__global__ __launch_bounds__(256) void kfused(
        const float* __restrict__ x,
        const short* __restrict__ Wg_bf, const short* __restrict__ Wc_bf32,
        const short* __restrict__ Wb_bf,
        const float* __restrict__ A, const float* __restrict__ bb,
        const float* __restrict__ bc, const float* __restrict__ bg,
        const float* __restrict__ Dv, const float* __restrict__ gamma,
        const float* __restrict__ beta, float* __restrict__ out) {
    __shared__ short xs[48][264];    // 25344 B: rows 0-15 warmup, 16-47 main (bf16)
    __shared__ float bxs[48][20];    //  3840 B: Bx + bias
    __shared__ short ss[32][16];     //  1024 B: states bf16
    __shared__ float red[32][4][2];  //  1024 B
    __shared__ float lnp[32][2];     //   256 B   -> 31488 B total
    const int tid = threadIdx.x;
    const long rowbase = (long)blockIdx.x * 32;
    const int t0 = (int)(rowbase & (SEQ - 1));      // 0 => exact start, no warmup
    const int w = tid >> 6, l = tid & 63;
    const int lr = l & 15, lk = l >> 4;
    const int c0 = w * 64;

    // ---- stage 48x256 fp32 -> bf16 LDS (16 warmup + 32 main rows) ----
    #pragma unroll
    for (int i = 0; i < 12; ++i) {
        int f = i * 1024 + tid * 4;
        int r = f >> 8, c = f & 255;
        short4 bv;
        if (t0 == 0 && r < 16) {                     // no warmup: zero rows
            bv.x = 0; bv.y = 0; bv.z = 0; bv.w = 0;
        } else {
            const float4 v = *(const float4*)(x + (rowbase - 16 + r) * 256 + c);
            bv.x = f2bf(v.x); bv.y = f2bf(v.y); bv.z = f2bf(v.z); bv.w = f2bf(v.w);
        }
        *(short4*)(&xs[r][c]) = bv;
    }
    __syncthreads();                                 // b1: xs ready

    // ---- Bx mini-GEMM: waves 1-3 compute tiles m=0..2 (48 rows x 16) ----
    if (w >= 1) {
        const int m = w - 1;
        f32x4 acc = {0.f, 0.f, 0.f, 0.f};
        #pragma unroll
        for (int k0 = 0; k0 < 256; k0 += 32) {
            bf16x8 a = *(const bf16x8*)(&xs[m * 16 + lr][k0 + lk * 8]);
            bf16x8 b = *(const bf16x8*)(Wb_bf + lr * 256 + k0 + lk * 8);
            acc = __builtin_amdgcn_mfma_f32_16x16x32_bf16(a, b, acc, 0, 0, 0);
        }
        const float bias = bb[lr];
        #pragma unroll
        for (int j = 0; j < 4; ++j)
            bxs[m * 16 + lk * 4 + j][lr] = acc[j] + bias;   // row=lk*4+j, col=lr
    }
    __syncthreads();                                 // b2: bxs ready

    // ---- serial scan: wave0 lanes 0-15, 48 steps (16 warmup + 32) ----
    if (tid < 16) {
        const int n = tid;
        float a[16];
        #pragma unroll
        for (int k = 0; k < 16; ++k) a[k] = A[n * 16 + (n ^ k)];
        float s = 0.f;
        const int start = (t0 == 0) ? 16 : 0;        // t0==0: exact zero init
        for (int st = start; st < 48; ++st) {
            const float bx = bxs[st][n];
            float z0 = bx + a[0] * s;
            float z1 = a[1] * __shfl_xor(s, 1, 16);
            float z2 = a[2] * __shfl_xor(s, 2, 16);
            float z3 = a[3] * __shfl_xor(s, 3, 16);
            #pragma unroll
            for (int k = 4; k < 16; k += 4) {
                z0 += a[k + 0] * __shfl_xor(s, k + 0, 16);
                z1 += a[k + 1] * __shfl_xor(s, k + 1, 16);
                z2 += a[k + 2] * __shfl_xor(s, k + 2, 16);
                z3 += a[k + 3] * __shfl_xor(s, k + 3, 16);
            }
            const float z = (z0 + z1) + (z2 + z3);
            const float e = __expf(2.0f * z);
            s = 1.0f - 2.0f / (e + 1.0f);            // tanh(z)
            if (st >= 16) ss[st - 16][n] = f2bf(s);
        }
    }

    // ---- gate GEMM: every wave its 64-col quad over 32 main rows ----
    f32x4 ag[2][4];
    #pragma unroll
    for (int i = 0; i < 2; ++i)
        #pragma unroll
        for (int j = 0; j < 4; ++j) ag[i][j] = (f32x4){0.f, 0.f, 0.f, 0.f};
    for (int k0 = 0; k0 < 256; k0 += 32) {
        bf16x8 a[2];
        #pragma unroll
        for (int rt = 0; rt < 2; ++rt)
            a[rt] = *(const bf16x8*)(&xs[16 + rt * 16 + lr][k0 + lk * 8]);
        #pragma unroll
        for (int ct = 0; ct < 4; ++ct) {
            bf16x8 bfr = *(const bf16x8*)(Wg_bf + (long)(c0 + ct * 16 + lr) * 256 + k0 + lk * 8);
            #pragma unroll
            for (int rt = 0; rt < 2; ++rt)
                ag[rt][ct] = __builtin_amdgcn_mfma_f32_16x16x32_bf16(a[rt], bfr, ag[rt][ct], 0, 0, 0);
        }
    }
    __syncthreads();                                 // b3: scan + all GEMMs done

    // ---- y-projection + mix (r8-proven), hh in-place into xs ----
    bf16x8 st_frag[2];
    #pragma unroll
    for (int rt = 0; rt < 2; ++rt)
        st_frag[rt] = *(const bf16x8*)(&ss[rt * 16 + lr][(lk & 1) * 8]);
    bf16x8 by[4];
    float bgv[4], bcv[4], dvv[4];
    #pragma unroll
    for (int ct = 0; ct < 4; ++ct) {
        int col = c0 + ct * 16 + lr;
        by[ct] = *(const bf16x8*)(Wc_bf32 + col * 32 + lk * 8);
        bgv[ct] = bg[col]; bcv[ct] = bc[col]; dvv[ct] = Dv[col];
    }
    #pragma unroll
    for (int rt = 0; rt < 2; ++rt) {
        f32x4 ay[4];
        #pragma unroll
        for (int ct = 0; ct < 4; ++ct) {
            f32x4 zz = {0.f, 0.f, 0.f, 0.f};
            ay[ct] = __builtin_amdgcn_mfma_f32_16x16x32_bf16(st_frag[rt], by[ct], zz, 0, 0, 0);
        }
        float psum[4], psq[4];
        #pragma unroll
        for (int j = 0; j < 4; ++j) { psum[j] = 0.f; psq[j] = 0.f; }
        #pragma unroll
        for (int ct = 0; ct < 4; ++ct) {
            #pragma unroll
            for (int j = 0; j < 4; ++j) {
                const int row = rt * 16 + lk * 4 + j;
                const int col = c0 + ct * 16 + lr;
                const float xf = bf2f(xs[16 + row][col]);
                const float zg = ag[rt][ct][j] + bgv[ct];
                const float g = zg / (1.0f + __expf(-zg));        // silu
                const float yv = ay[ct][j] + bcv[ct] + dvv[ct] * xf;
                const float hh = g * yv + (2.0f - g) * xf;        // out + x
                xs[16 + row][col] = f2bf(hh);                     // owner-only write
                psum[j] += hh; psq[j] += hh * hh;
            }
        }
        #pragma unroll
        for (int j = 0; j < 4; ++j) {
            float s1 = psum[j], s2 = psq[j];
            #pragma unroll
            for (int m = 1; m < 16; m <<= 1) {
                s1 += __shfl_xor(s1, m, 16);
                s2 += __shfl_xor(s2, m, 16);
            }
            if (lr == 0) {
                int row = rt * 16 + lk * 4 + j;
                red[row][w][0] = s1; red[row][w][1] = s2;
            }
        }
    }
    __syncthreads();                                 // b4
    if (tid < 32) {
        float s = 0.f, q = 0.f;
        #pragma unroll
        for (int wv = 0; wv < 4; ++wv) { s += red[tid][wv][0]; q += red[tid][wv][1]; }
        const float mu = s * (1.0f / 256.0f);
        const float var = q * (1.0f / 256.0f) - mu * mu;
        lnp[tid][0] = mu; lnp[tid][1] = rsqrtf(var + 1e-5f);
    }
    __syncthreads();                                 // b5

    // ---- coalesced LN epilogue: 1KB-contiguous float4 stores per wave-inst ----
    const int cc = (tid * 4) & 255;
    const int rb2 = tid >> 6;
    const float4 gm = *(const float4*)(gamma + cc);
    const float4 bt = *(const float4*)(beta + cc);
    #pragma unroll
    for (int i = 0; i < 8; ++i) {
        const int r = i * 4 + rb2;
        const float mu = lnp[r][0], rs = lnp[r][1];
        short4 h4 = *(const short4*)(&xs[16 + r][cc]);
        float4 o;
        o.x = (bf2f(h4.x) - mu) * rs * gm.x + bt.x;
        o.y = (bf2f(h4.y) - mu) * rs * gm.y + bt.y;
        o.z = (bf2f(h4.z) - mu) * rs * gm.z + bt.z;
        o.w = (bf2f(h4.w) - mu) * rs * gm.w + bt.w;
        *(float4*)(out + (rowbase + r) * 256 + cc) = o;
    }
}

extern "C" void kernel_launch(void* const* d_in, const int* in_sizes, int n_in,
                              void* d_out, int out_size, void* d_ws, size_t ws_size,
                              hipStream_t stream) {
    const float* x     = (const float*)d_in[0];
    const float* A     = (const float*)d_in[1];
    const float* Wb    = (const float*)d_in[2];
    const float* bb    = (const float*)d_in[3];
    const float* Wc    = (const float*)d_in[4];
    const float* bc    = (const float*)d_in[5];
    const float* Wg    = (const float*)d_in[6];
    const float* bg    = (const float*)d_in[7];
    const float* Dv    = (const float*)d_in[8];
    const float* gamma = (const float*)d_in[9];
    const float* beta  = (const float*)d_in[10];
    float* out = (float*)d_out;

    char* ws = (char*)d_ws;
    short* Wg_bf   = (short*)(ws);                  // 131,072 B
    short* Wc_bf32 = (short*)(ws + 131072);         //  16,384 B
    short* Wb_bf   = (short*)(ws + 147456);         //   8,192 B

    k0_convert<<<64, 256, 0, stream>>>(Wg, Wc, Wb, Wg_bf, Wc_bf32, Wb_bf);
    kfused<<<4096, 256, 0, stream>>>(x, Wg_bf, Wc_bf32, Wb_bf, A, bb, bc, bg,
                                     Dv, gamma, beta, out);
}

// Round 12
// 147.690 us; speedup vs baseline: 1.3481x; 1.3481x over previous
//
#include <hip/hip_runtime.h>
#include <hip/hip_bf16.h>

#define DM 256
#define DSZ 16
#define SEQ 4096

typedef __attribute__((ext_vector_type(8))) short bf16x8;
typedef __attribute__((ext_vector_type(4))) float f32x4;

__device__ inline short f2bf(float f) {
    union { float f; unsigned u; } v; v.f = f;
    unsigned r = v.u + 0x7fff + ((v.u >> 16) & 1);   // RNE
    return (short)(r >> 16);
}
__device__ inline float bf2f(short s) {
    union { unsigned u; float f; } v;
    v.u = ((unsigned)(unsigned short)s) << 16;
    return v.f;
}

// ---------------- K0: convert weights to bf16 (Wc zero-padded K=16->32) ----
__global__ __launch_bounds__(256) void k0_convert(
        const float* __restrict__ Wg, const float* __restrict__ Wc,
        const float* __restrict__ Wb,
        short* __restrict__ Wg_bf, short* __restrict__ Wc_bf32,
        short* __restrict__ Wb_bf) {
    int i = blockIdx.x * 256 + threadIdx.x;
    int stride = gridDim.x * 256;
    for (int idx = i; idx < 256 * 256; idx += stride) Wg_bf[idx] = f2bf(Wg[idx]);
    for (int idx = i; idx < 256 * 32; idx += stride) {
        int c = idx >> 5, k = idx & 31;
        Wc_bf32[idx] = (k < 16) ? f2bf(Wc[c * 16 + k]) : (short)0;
    }
    for (int idx = i; idx < 16 * 256; idx += stride) Wb_bf[idx] = f2bf(Wb[idx]);
}

// ---------------- K1: Bx = x @ Wb^T + bb  (fp32 out, no sidecar) -----------
__global__ __launch_bounds__(256) void k1_bx(
        const float* __restrict__ x, const short* __restrict__ Wb_bf,
        const float* __restrict__ bb, float* __restrict__ Bx) {
    __shared__ short xs[64][264];   // row stride 528B (16B aligned)
    const int tid = threadIdx.x;
    const long rowbase = (long)blockIdx.x * 64;
    #pragma unroll
    for (int i = 0; i < 16; ++i) {
        int f = i * 1024 + tid * 4;
        const float4 v = *(const float4*)(x + rowbase * 256 + f);
        int r = f >> 8, c = f & 255;
        short4 bv; bv.x = f2bf(v.x); bv.y = f2bf(v.y); bv.z = f2bf(v.z); bv.w = f2bf(v.w);
        *(short4*)(&xs[r][c]) = bv;
    }
    __syncthreads();
    const int w = tid >> 6, l = tid & 63;
    const int lr = l & 15, lk = l >> 4;
    f32x4 acc = {0.f, 0.f, 0.f, 0.f};
    #pragma unroll
    for (int k0 = 0; k0 < 256; k0 += 32) {
        bf16x8 a = *(const bf16x8*)(&xs[w * 16 + lr][k0 + lk * 8]);
        bf16x8 b = *(const bf16x8*)(Wb_bf + lr * 256 + k0 + lk * 8);
        acc = __builtin_amdgcn_mfma_f32_16x16x32_bf16(a, b, acc, 0, 0, 0);
    }
    const float bias = bb[lr];
    #pragma unroll
    for (int j = 0; j < 4; ++j) {
        int row = w * 16 + lk * 4 + j;        // C layout: col=lr, row=lk*4+j
        Bx[(rowbase + row) * 16 + lr] = acc[j] + bias;
    }
}

// ---------------- K2: chunked (truncated-memory) scan ----------------------
// s_t = tanh(A s_{t-1} + Bx_t). ||A||inf ~0.13 -> 16-step warmup error ~1e-14.
__global__ __launch_bounds__(256) void k2_scan(
        const float* __restrict__ Bx, const float* __restrict__ A,
        short* __restrict__ st_bf) {
    const int tid = threadIdx.x;
    const int unit = blockIdx.x * 16 + (tid >> 4);  // 0..2047 = 32 b x 64 chunks
    const int n = tid & 15;
    const int b = unit >> 6;
    const int c = unit & 63;
    float a[16];
    #pragma unroll
    for (int k = 0; k < 16; ++k) a[k] = A[n * 16 + (n ^ k)];
    const int tbeg = c * 64;
    const int t0 = tbeg - 16;                 // 16-step warmup from zero state
    const float* bxp = Bx + (long)b * SEQ * 16 + n;
    short* op = st_bf + ((long)b * SEQ + tbeg) * 16 + n;

    float buf[8];
    #pragma unroll
    for (int j = 0; j < 8; ++j) {
        int t = t0 + j;
        int tc = t < 0 ? 0 : t;
        float v = bxp[(long)tc * 16];
        buf[j] = (t < 0) ? 0.0f : v;
    }
    float s = 0.0f;
    for (int g = 0; g < 10; ++g) {
        #pragma unroll
        for (int j = 0; j < 8; ++j) {
            const int t = t0 + g * 8 + j;
            const float bx = buf[j];
            { // prefetch 8 ahead
                int tp = t0 + (g + 1) * 8 + j;
                int tc = tp < 0 ? 0 : (tp > SEQ - 1 ? SEQ - 1 : tp);
                float v = bxp[(long)tc * 16];
                buf[j] = (tp < 0) ? 0.0f : v;
            }
            float z0 = bx + a[0] * s;
            float z1 = a[1] * __shfl_xor(s, 1, 16);
            float z2 = a[2] * __shfl_xor(s, 2, 16);
            float z3 = a[3] * __shfl_xor(s, 3, 16);
            #pragma unroll
            for (int k = 4; k < 16; k += 4) {
                z0 += a[k + 0] * __shfl_xor(s, k + 0, 16);
                z1 += a[k + 1] * __shfl_xor(s, k + 1, 16);
                z2 += a[k + 2] * __shfl_xor(s, k + 2, 16);
                z3 += a[k + 3] * __shfl_xor(s, k + 3, 16);
            }
            const float z = (z0 + z1) + (z2 + z3);
            const float e = __expf(2.0f * z);
            s = 1.0f - 2.0f / (e + 1.0f);      // tanh(z)
            if (t >= tbeg) op[(long)(t - tbeg) * 16] = f2bf(s);
        }
    }
}

// ---------------- K3: fused gate GEMM + y + mix + LayerNorm ----------------
// r8-proven structure: 32-row tile, early reg loads, in-place hh,
// coalesced epilogue. NEW: nontemporal out stores (keep x L3-resident).
__global__ __launch_bounds__(256) void k3_fused(
        const float* __restrict__ x, const short* __restrict__ Wg_bf,
        const short* __restrict__ Wc_bf32, const short* __restrict__ st_bf,
        const float* __restrict__ bc, const float* __restrict__ bg,
        const float* __restrict__ Dv, const float* __restrict__ gamma,
        const float* __restrict__ beta, float* __restrict__ out) {
    __shared__ short xs[32][264];    // 16896 B (x tile; overwritten by hh)
    __shared__ float red[32][4][2];  //  1024 B
    __shared__ float lnp[32][2];     //   256 B  -> ~18.2 KB
    const int tid = threadIdx.x;
    const long rowbase = (long)blockIdx.x * 32;

    const int w = tid >> 6, l = tid & 63;
    const int lr = l & 15, lk = l >> 4;
    const int c0 = w * 64;

    // ---- early register loads (latency hidden under staging + GEMM) ----
    bf16x8 st_frag[2];
    #pragma unroll
    for (int rt = 0; rt < 2; ++rt)
        st_frag[rt] = *(const bf16x8*)(st_bf + (rowbase + rt * 16 + lr) * 16 + (lk & 1) * 8);
    bf16x8 by[4];
    float bgv[4], bcv[4], dvv[4];
    #pragma unroll
    for (int ct = 0; ct < 4; ++ct) {
        int col = c0 + ct * 16 + lr;
        by[ct] = *(const bf16x8*)(Wc_bf32 + col * 32 + lk * 8);
        bgv[ct] = bg[col]; bcv[ct] = bc[col]; dvv[ct] = Dv[col];
    }

    // ---- stage 32x256 x tile as bf16 ----
    #pragma unroll
    for (int i = 0; i < 8; ++i) {
        int f = i * 1024 + tid * 4;
        const float4 v = *(const float4*)(x + rowbase * 256 + f);
        short4 bv; bv.x = f2bf(v.x); bv.y = f2bf(v.y); bv.z = f2bf(v.z); bv.w = f2bf(v.w);
        *(short4*)(&xs[f >> 8][f & 255]) = bv;
    }
    __syncthreads();                          // b1

    f32x4 ag[2][4];
    #pragma unroll
    for (int i = 0; i < 2; ++i)
        #pragma unroll
        for (int j = 0; j < 4; ++j) ag[i][j] = (f32x4){0.f, 0.f, 0.f, 0.f};

    for (int k0 = 0; k0 < 256; k0 += 32) {    // gate GEMM: 32x64 per wave
        bf16x8 a[2];
        #pragma unroll
        for (int rt = 0; rt < 2; ++rt)
            a[rt] = *(const bf16x8*)(&xs[rt * 16 + lr][k0 + lk * 8]);
        #pragma unroll
        for (int ct = 0; ct < 4; ++ct) {
            bf16x8 bfr = *(const bf16x8*)(Wg_bf + (long)(c0 + ct * 16 + lr) * 256 + k0 + lk * 8);
            #pragma unroll
            for (int rt = 0; rt < 2; ++rt)
                ag[rt][ct] = __builtin_amdgcn_mfma_f32_16x16x32_bf16(a[rt], bfr, ag[rt][ct], 0, 0, 0);
        }
    }
    __syncthreads();                          // b2: all reads of xs done

    #pragma unroll
    for (int rt = 0; rt < 2; ++rt) {
        f32x4 ay[4];
        #pragma unroll
        for (int ct = 0; ct < 4; ++ct) {
            f32x4 zz = {0.f, 0.f, 0.f, 0.f};
            ay[ct] = __builtin_amdgcn_mfma_f32_16x16x32_bf16(st_frag[rt], by[ct], zz, 0, 0, 0);
        }
        float psum[4], psq[4];
        #pragma unroll
        for (int j = 0; j < 4; ++j) { psum[j] = 0.f; psq[j] = 0.f; }
        #pragma unroll
        for (int ct = 0; ct < 4; ++ct) {
            #pragma unroll
            for (int j = 0; j < 4; ++j) {
                const int row = rt * 16 + lk * 4 + j;
                const int col = c0 + ct * 16 + lr;
                const float xf = bf2f(xs[row][col]);              // LDS
                const float zg = ag[rt][ct][j] + bgv[ct];
                const float g = zg / (1.0f + __expf(-zg));        // silu
                const float yv = ay[ct][j] + bcv[ct] + dvv[ct] * xf;
                const float hh = g * yv + (2.0f - g) * xf;        // out + x
                xs[row][col] = f2bf(hh);                          // in-place
                psum[j] += hh; psq[j] += hh * hh;
            }
        }
        #pragma unroll
        for (int j = 0; j < 4; ++j) {
            float s1 = psum[j], s2 = psq[j];
            #pragma unroll
            for (int m = 1; m < 16; m <<= 1) {
                s1 += __shfl_xor(s1, m, 16);
                s2 += __shfl_xor(s2, m, 16);
            }
            if (lr == 0) {
                int row = rt * 16 + lk * 4 + j;
                red[row][w][0] = s1; red[row][w][1] = s2;
            }
        }
    }
    __syncthreads();                          // b3
    if (tid < 32) {
        float s = 0.f, q = 0.f;
        #pragma unroll
        for (int wv = 0; wv < 4; ++wv) { s += red[tid][wv][0]; q += red[tid][wv][1]; }
        const float mu = s * (1.0f / 256.0f);
        const float var = q * (1.0f / 256.0f) - mu * mu;
        lnp[tid][0] = mu; lnp[tid][1] = rsqrtf(var + 1e-5f);
    }
    __syncthreads();                          // b4

    // coalesced LN epilogue; NONTEMPORAL stores keep x resident in L3
    const int cc = (tid * 4) & 255;
    const int rb2 = tid >> 6;
    const float4 gm = *(const float4*)(gamma + cc);
    const float4 bt = *(const float4*)(beta + cc);
    #pragma unroll
    for (int i = 0; i < 8; ++i) {
        const int r = i * 4 + rb2;
        const float mu = lnp[r][0], rs = lnp[r][1];
        short4 h4 = *(const short4*)(&xs[r][cc]);
        f32x4 o;
        o[0] = (bf2f(h4.x) - mu) * rs * gm.x + bt.x;
        o[1] = (bf2f(h4.y) - mu) * rs * gm.y + bt.y;
        o[2] = (bf2f(h4.z) - mu) * rs * gm.z + bt.z;
        o[3] = (bf2f(h4.w) - mu) * rs * gm.w + bt.w;
        __builtin_nontemporal_store(o, (f32x4*)(out + rowbase * 256 + (long)r * 256 + cc));
    }
}

extern "C" void kernel_launch(void* const* d_in, const int* in_sizes, int n_in,
                              void* d_out, int out_size, void* d_ws, size_t ws_size,
                              hipStream_t stream) {
    const float* x     = (const float*)d_in[0];
    const float* A     = (const float*)d_in[1];
    const float* Wb    = (const float*)d_in[2];
    const float* bb    = (const float*)d_in[3];
    const float* Wc    = (const float*)d_in[4];
    const float* bc    = (const float*)d_in[5];
    const float* Wg    = (const float*)d_in[6];
    const float* bg    = (const float*)d_in[7];
    const float* Dv    = (const float*)d_in[8];
    const float* gamma = (const float*)d_in[9];
    const float* beta  = (const float*)d_in[10];
    float* out = (float*)d_out;

    char* ws = (char*)d_ws;
    float* Bx      = (float*)(ws);                  //  8,388,608 B
    short* st_bf   = (short*)(ws + 8388608);        //  4,194,304 B
    short* Wg_bf   = (short*)(ws + 12582912);       //    131,072 B
    short* Wc_bf32 = (short*)(ws + 12713984);       //     16,384 B
    short* Wb_bf   = (short*)(ws + 12730368);       //      8,192 B

    k0_convert<<<64, 256, 0, stream>>>(Wg, Wc, Wb, Wg_bf, Wc_bf32, Wb_bf);
    k1_bx<<<2048, 256, 0, stream>>>(x, Wb_bf, bb, Bx);
    k2_scan<<<128, 256, 0, stream>>>(Bx, A, st_bf);
    k3_fused<<<4096, 256, 0, stream>>>(x, Wg_bf, Wc_bf32, st_bf, bc, bg, Dv,
                                       gamma, beta, out);
}